// Round 7
// baseline (176.812 us; speedup 1.0000x reference)
//
#include <hip/hip_runtime.h>
#include <hip/hip_bf16.h>

typedef unsigned short u16;
typedef __attribute__((ext_vector_type(8))) short short8v;   // 8 bf16 (4 VGPR)
typedef __attribute__((ext_vector_type(4))) float float4v;   // 4 f32 acc

__device__ inline u16 f2b(float f) {
  __hip_bfloat16 h = __float2bfloat16(f);
  union { __hip_bfloat16 h; u16 s; } u;
  u.h = h;
  return u.s;
}

__device__ inline float b2f(u16 s) {
  union { u16 s[2]; float f; } u;
  u.s[0] = 0; u.s[1] = s;
  return u.f;
}

__device__ inline void gload_lds16(const u16* g, u16* l) {
  __builtin_amdgcn_global_load_lds(
      (const __attribute__((address_space(1))) void*)g,
      (__attribute__((address_space(3))) void*)l, 16, 0, 0);
}

// ---------------------------------------------------------------------------
// fp32 -> bf16 conversion (vectorized, grid-stride)
// ---------------------------------------------------------------------------
__global__ __launch_bounds__(256) void cvt_f32_bf16(const float* __restrict__ in,
                                                    u16* __restrict__ out, int n4) {
  for (int i = blockIdx.x * blockDim.x + threadIdx.x; i < n4;
       i += gridDim.x * blockDim.x) {
    float4 v = ((const float4*)in)[i];
    ushort4 o;
    o.x = f2b(v.x); o.y = f2b(v.y); o.z = f2b(v.z); o.w = f2b(v.w);
    ((ushort4*)out)[i] = o;
  }
}

// ---------------------------------------------------------------------------
// gemm7: C[m][n] = sum_k A[m][k]*B[n][k], both row-major K-contiguous.
// BM=256, BN=128, BK=32. 256 threads = 4 waves (2Mx2N), wave tile 128x64
// (42.7 FLOP per LDS byte vs 32 for 64x64 -> LDS-BW cap ~67-80% MfmaUtil).
// 3 LDS buffers x 24 KB = 72 KB -> 2 blocks/CU (co-residency covers stalls).
// Depth-2 prefetch: during tile t stage tile t+2; top-of-tile waits
// vmcnt(6) (tile t's 6 loads retired, t+1's stay in flight ~2 tiles).
// One barrier / one vmcnt / one lgkm wait per K-tile.
// LDS layout: 2 rows per 128-B line, 8x16B slots XOR-swizzled by line&7
// (16-lane access groups hit each 4-bank group exactly 2x = conflict-free).
// Staged via linear global_load_lds dest + inverse-swizzled global source.
// MODE: 0 none; 1 skip tile if n0 > m0+256 (scores); 2 cap K at m0+257
//       (PV; A zero-padded by softmax to staged extent), bx heavy-first.
// ---------------------------------------------------------------------------
template <int MODE, typename CT>
__global__ __launch_bounds__(256, 2)
void gemm7(const u16* __restrict__ A, int lda, long sA,
           const u16* __restrict__ B, int ldb, long sB,
           CT* __restrict__ C, int ldc, long sC, int K) {
  constexpr int BM = 256, BN = 128, BK = 32;
  constexpr int A_U16 = BM * BK;                   // 8192 (16 KiB)
  constexpr int BUF_U16 = (BM + BN) * BK;          // 12288 (24 KiB)
  constexpr int BUF_BYTES = BUF_U16 * 2;
  __shared__ __align__(16) u16 lds[3 * BUF_U16];   // 72 KiB

  const int z = blockIdx.z;
  A += (long)z * sA;
  B += (long)z * sB;

  int bx = blockIdx.x;
  if (MODE == 2) bx = gridDim.x - 1 - bx;          // heavy tiles first
  const int m0 = bx * BM;
  const int n0 = blockIdx.y * BN;
  if (MODE == 1 && n0 > m0 + BM) return;           // fully masked tile
  int Keff = K;
  if (MODE == 2) Keff = min(m0 + BM + 1, K);
  const int nk = (Keff + BK - 1) / BK;

  const int tid  = threadIdx.x;
  const int lane = tid & 63;
  const int wid  = tid >> 6;
  const int wr   = wid >> 1;                       // 0..1 (M)
  const int wc   = wid & 1;                        // 0..1 (N)

  // staging map: chunk c = 16B at LDS byte 16c (region-local).
  // line L = c>>3 holds rows 2L,2L+1; phys slot p = c&7 holds logical slot
  // l = p ^ (L&7); l -> row 2L + (l>>2), k-group (l&3)*8 elems.
  const u16* gsrc[6];
  int loff[6];
#pragma unroll
  for (int j = 0; j < 4; ++j) {                    // A: 1024 chunks
    int c = tid + j * 256;
    int L = c >> 3, p = c & 7, l = p ^ (L & 7);
    int r = 2 * L + (l >> 2), kg = (l & 3) * 8;
    gsrc[j] = A + (long)(m0 + r) * lda + kg;
    loff[j] = c * 8;
  }
#pragma unroll
  for (int j = 0; j < 2; ++j) {                    // B: 512 chunks
    int c = tid + j * 256;
    int L = c >> 3, p = c & 7, l = p ^ (L & 7);
    int r = 2 * L + (l >> 2), kg = (l & 3) * 8;
    gsrc[4 + j] = B + (long)(n0 + r) * ldb + kg;
    loff[4 + j] = A_U16 + c * 8;
  }

#define STAGE(T_, BUF_)                                                     \
  {                                                                         \
    u16* base_ = lds + (BUF_) * BUF_U16;                                    \
    _Pragma("unroll")                                                       \
    for (int s = 0; s < 6; ++s)                                             \
      gload_lds16(gsrc[s] + (T_) * BK, base_ + loff[s]);                    \
  }

  // ds_read swizzled byte offsets (within buffer)
  const int g    = lane >> 4;                      // k-group 0..3
  const int rA0  = wr * 128 + (lane & 15);
  const int rB0  = wc * 64 + (lane & 15);
  const int lA0  = rA0 >> 1, lB0 = rB0 >> 1;
  const int cA0  = ((rA0 & 1) << 2) | g;
  const int cB0  = ((rB0 & 1) << 2) | g;
  const int offA0 = lA0 * 128 + 16 * (cA0 ^ (lA0 & 7));
  const int offB0 = 2 * A_U16 + lB0 * 128 + 16 * (cB0 ^ (lB0 & 7));
  // mi/ni stride: +16 rows = +8 lines = +1024 B (line&7, row parity invariant)

  float4v acc[8][4];
#pragma unroll
  for (int i = 0; i < 8; ++i)
#pragma unroll
    for (int j = 0; j < 4; ++j)
      acc[i][j] = (float4v){0.f, 0.f, 0.f, 0.f};

  // prologue: stage tiles 0,1 into bufs 0,1
  STAGE(0, 0);
  if (nk > 1) STAGE(1, 1);

  int cur = 0;
  for (int t = 0; t < nk; ++t) {
    if (t + 1 < nk) asm volatile("s_waitcnt vmcnt(6)" ::: "memory");
    else            asm volatile("s_waitcnt vmcnt(0)" ::: "memory");
    __builtin_amdgcn_s_barrier();                  // tile t visible; buf
                                                   // (t+2)%3 free for staging
    const char* bb = (const char*)lds + cur * BUF_BYTES;
    short8v a[8], b[4];
#pragma unroll
    for (int mi = 0; mi < 8; ++mi)
      a[mi] = *(const short8v*)(bb + offA0 + mi * 1024);
#pragma unroll
    for (int ni = 0; ni < 4; ++ni)
      b[ni] = *(const short8v*)(bb + offB0 + ni * 1024);

    const int nxt2 = (cur >= 1) ? cur - 1 : 2;     // (cur+2)%3
    if (t + 2 < nk) STAGE(t + 2, nxt2);

    asm volatile("s_waitcnt lgkmcnt(0)" ::: "memory");
    __builtin_amdgcn_sched_barrier(0);
    __builtin_amdgcn_s_setprio(1);
#pragma unroll
    for (int mi = 0; mi < 8; ++mi)
#pragma unroll
      for (int ni = 0; ni < 4; ++ni)
        acc[mi][ni] = __builtin_amdgcn_mfma_f32_16x16x32_bf16(
            a[mi], b[ni], acc[mi][ni], 0, 0, 0);
    __builtin_amdgcn_s_setprio(0);

    cur = (cur < 2) ? cur + 1 : 0;
  }
#undef STAGE

  // epilogue: C/D layout col = lane&15, row = (lane>>4)*4 + reg
  CT* c = C + (long)z * sC;
  const int r0base = m0 + wr * 128 + ((lane >> 4) << 2);
  const int cbase  = n0 + wc * 64 + (lane & 15);
#pragma unroll
  for (int mi = 0; mi < 8; ++mi) {
#pragma unroll
    for (int ni = 0; ni < 4; ++ni) {
      const int r0 = r0base + mi * 16;
      const int cc = cbase + ni * 16;
#pragma unroll
      for (int r = 0; r < 4; ++r) {
        float v = acc[mi][ni][r];
        if constexpr (__is_same(CT, float)) c[(long)(r0 + r) * ldc + cc] = v;
        else                                c[(long)(r0 + r) * ldc + cc] = f2b(v);
      }
    }
  }
}

// ---------------------------------------------------------------------------
// masked scaled softmax, in place on bf16 S (one row per block, B*T blocks).
// Row i sees j <= i+1; scale = 1/32. Zero-pads P up to the PV staged extent
// (tile base + 288, BM=256/BK=32).
// ---------------------------------------------------------------------------
__global__ __launch_bounds__(256)
void softmax_kernel(u16* __restrict__ SP, int T) {
  const int  i    = blockIdx.x & (T - 1);
  const long base = (long)blockIdx.x * T;
  const int  nvis = min(i + 2, T);
  const int  capJ = min(T, ((i >> 8) << 8) + 288);  // PV staging extent
  const float scale = 0.03125f;

  __shared__ float red[4];

  const int j0 = threadIdx.x * 8;
  float v[8];
  float m = -INFINITY;
  if (j0 < nvis) {
    short8v raw = *(const short8v*)&SP[base + j0];
#pragma unroll
    for (int e = 0; e < 8; ++e) {
      float f = (j0 + e < nvis) ? b2f((u16)raw[e]) * scale : -INFINITY;
      v[e] = f;
      m = fmaxf(m, f);
    }
  }
#pragma unroll
  for (int o = 32; o; o >>= 1) m = fmaxf(m, __shfl_xor(m, o));
  const int wid = threadIdx.x >> 6;
  if ((threadIdx.x & 63) == 0) red[wid] = m;
  __syncthreads();
  m = fmaxf(fmaxf(red[0], red[1]), fmaxf(red[2], red[3]));
  __syncthreads();

  float s = 0.f;
  if (j0 < nvis) {
#pragma unroll
    for (int e = 0; e < 8; ++e) {
      float p = (j0 + e < nvis) ? __expf(v[e] - m) : 0.f;
      v[e] = p;
      s += p;
    }
  }
#pragma unroll
  for (int o = 32; o; o >>= 1) s += __shfl_xor(s, o);
  if ((threadIdx.x & 63) == 0) red[wid] = s;
  __syncthreads();
  s = red[0] + red[1] + red[2] + red[3];
  const float inv = 1.0f / s;

  if (j0 < capJ) {
    short8v o8;
#pragma unroll
    for (int e = 0; e < 8; ++e)
      o8[e] = (short)f2b((j0 + e < nvis) ? v[e] * inv : 0.f);
    *(short8v*)&SP[base + j0] = o8;
  }
}

// ---------------------------------------------------------------------------
extern "C" void kernel_launch(void* const* d_in, const int* in_sizes, int n_in,
                              void* d_out, int out_size, void* d_ws, size_t ws_size,
                              hipStream_t stream) {
  const float* x  = (const float*)d_in[0];
  const float* Wq = (const float*)d_in[1];
  const float* Wk = (const float*)d_in[2];
  const float* Wv = (const float*)d_in[3];
  float* out = (float*)d_out;

  const int B = 4, T = 2048, D = 1024;
  const int M = B * T;          // 8192
  const long TT = (long)T * T;  // 4 Mi elements

  char* ws = (char*)d_ws;
  u16* qk  = (u16*)(ws);                      // 32 MiB: [8192][2048], q|k
  u16* vt  = (u16*)(ws + (32l << 20));        // 16 MiB: [1024][8192] d-major
  u16* xb  = (u16*)(ws + (48l << 20));        // 16 MiB (dead after vt GEMM)
  u16* wqk = (u16*)(ws + (64l << 20));        //  4 MiB: [2048][1024]
  u16* wv  = (u16*)(ws + (68l << 20));        //  2 MiB
  u16* S   = (u16*)(ws + (48l << 20));        // 32 MiB: 4 x [2048][2048] bf16
                                              //   (overlaps xb/wqk/wv; written
                                              //    only after they are dead)
  // peak: 80 MiB

  // fp32 -> bf16
  cvt_f32_bf16<<<2048, 256, 0, stream>>>(x,  xb,  (M * D) / 4);
  cvt_f32_bf16<<<512,  256, 0, stream>>>(Wq, wqk,               (D * D) / 4);
  cvt_f32_bf16<<<512,  256, 0, stream>>>(Wk, wqk + (long)D * D, (D * D) / 4);
  cvt_f32_bf16<<<512,  256, 0, stream>>>(Wv, wv,  (D * D) / 4);

  // qk = x @ [Wq;Wk]^T  (8192 x 2048): grid 32x16 = 512 blocks (2/CU)
  gemm7<0, u16><<<dim3(M / 256, 2 * D / 128, 1), 256, 0, stream>>>(
      xb, D, 0, wqk, D, 0, qk, 2 * D, 0, D);
  // vt = Wv @ x^T  (1024 x 8192, d-major): grid 4x64 = 256 blocks
  gemm7<0, u16><<<dim3(D / 256, M / 128, 1), 256, 0, stream>>>(
      wv, D, 0, xb, D, 0, vt, M, 0, D);

  // S_b = q_b k_b^T (bf16, tile-skip above diagonal): grid 8x16x4, 316 live
  gemm7<1, u16><<<dim3(T / 256, T / 128, B), 256, 0, stream>>>(
      qk, 2 * D, (long)T * 2 * D,
      qk + D, 2 * D, (long)T * 2 * D,
      S, T, TT, D);

  // softmax in place (S -> P), all rows of all batches
  softmax_kernel<<<B * T, 256, 0, stream>>>(S, T);

  // O_b = P_b V_b = P_b (vt_b)^T, K capped per tile-row: grid 8x8x4
  gemm7<2, float><<<dim3(T / 256, D / 128, B), 256, 0, stream>>>(
      S, T, TT,
      vt, M, T,
      out, D, (long)T * D, T);
}

// Round 8
// 161.842 us; speedup vs baseline: 1.0925x; 1.0925x over previous
//
#include <hip/hip_runtime.h>
#include <hip/hip_bf16.h>

typedef unsigned short u16;
typedef __attribute__((ext_vector_type(8))) short short8v;   // 8 bf16 (4 VGPR)
typedef __attribute__((ext_vector_type(4))) float float4v;   // 4 f32 acc

__device__ inline u16 f2b(float f) {
  __hip_bfloat16 h = __float2bfloat16(f);
  union { __hip_bfloat16 h; u16 s; } u;
  u.h = h;
  return u.s;
}

__device__ inline float b2f(u16 s) {
  union { u16 s[2]; float f; } u;
  u.s[0] = 0; u.s[1] = s;
  return u.f;
}

__device__ inline void gload_lds16(const u16* g, u16* l) {
  __builtin_amdgcn_global_load_lds(
      (const __attribute__((address_space(1))) void*)g,
      (__attribute__((address_space(3))) void*)l, 16, 0, 0);
}

// ---------------------------------------------------------------------------
// fp32 -> bf16 conversion (vectorized, grid-stride)
// ---------------------------------------------------------------------------
__global__ __launch_bounds__(256) void cvt_f32_bf16(const float* __restrict__ in,
                                                    u16* __restrict__ out, int n4) {
  for (int i = blockIdx.x * blockDim.x + threadIdx.x; i < n4;
       i += gridDim.x * blockDim.x) {
    float4 v = ((const float4*)in)[i];
    ushort4 o;
    o.x = f2b(v.x); o.y = f2b(v.y); o.z = f2b(v.z); o.w = f2b(v.w);
    ((ushort4*)out)[i] = o;
  }
}

// fused 3-matrix weight conversion (one dispatch instead of three)
__global__ __launch_bounds__(256)
void cvt_w3(const float* __restrict__ wa, const float* __restrict__ wb,
            const float* __restrict__ wc, u16* __restrict__ oa,
            u16* __restrict__ ob, u16* __restrict__ oc, int n4each) {
  int i = blockIdx.x * blockDim.x + threadIdx.x;
  const float* src; u16* dst; int off;
  if (i < n4each)            { src = wa; dst = oa; off = i; }
  else if (i < 2 * n4each)   { src = wb; dst = ob; off = i - n4each; }
  else                       { src = wc; dst = oc; off = i - 2 * n4each; }
  float4 v = ((const float4*)src)[off];
  ushort4 o;
  o.x = f2b(v.x); o.y = f2b(v.y); o.z = f2b(v.z); o.w = f2b(v.w);
  ((ushort4*)dst)[off] = o;
}

// ---------------------------------------------------------------------------
// gemm8: C[m][n] = sum_k A[m][k]*B[n][k], both row-major K-contiguous.
// 128x128 tile, BK=64, 256 threads = 4 waves (2x2), 64x64 per wave.
// 2-buffer LDS (64 KB -> 2 blocks/CU).  Per K-tile:
//   stage(t+1) issued FIRST (max vmcnt slack) ->
//   16 ds_reads in two pinned groups (slice0 | sched_barrier | slice1) ->
//   lgkmcnt(8): slice0 landed -> 16 MFMA slice0 (slice1 reads land in its
//   shadow) -> lgkmcnt(0) -> 16 MFMA slice1 -> vmcnt(0) -> s_barrier.
// Intra-tile read/MFMA overlap removes the ~512cy LDS burst from the
// critical path (r6 serialized them -> 31% MfmaUtil).
// XOR swizzle byte^=(row&7)<<4 via pre-swizzled global source (linear
// global_load_lds dest) + swizzled ds_reads (0 conflicts, verified r3-r7).
// MODE: 0 none; 1 skip tile if n0 > m0+128 (scores); 2 cap K at m0+129
//       (PV; A zero-padded by softmax to staged extent), bx heavy-first.
// ---------------------------------------------------------------------------
template <int MODE, typename CT>
__global__ __launch_bounds__(256, 2)
void gemm8(const u16* __restrict__ A, int lda, long sA,
           const u16* __restrict__ B, int ldb, long sB,
           CT* __restrict__ C, int ldc, long sC, int K) {
  constexpr int BM = 128, BN = 128;
  constexpr int A_U16 = BM * 64;                  // 8192
  constexpr int TILE_U16 = (BM + BN) * 64;        // 16384
  constexpr int TILE_BYTES = TILE_U16 * 2;        // 32768
  __shared__ __align__(16) u16 lds[2 * TILE_U16]; // 64 KiB

  const int z = blockIdx.z;
  A += (long)z * sA;
  B += (long)z * sB;

  int bx = blockIdx.x;
  if (MODE == 2) bx = gridDim.x - 1 - bx;         // heavy tiles first
  const int m0 = bx * BM;
  const int n0 = blockIdx.y * BN;
  if (MODE == 1 && n0 > m0 + BM) return;          // fully masked tile
  int Keff = K;
  if (MODE == 2) Keff = min(m0 + BM + 1, K);
  const int nk = (Keff + 63) >> 6;

  const int tid  = threadIdx.x;
  const int lane = tid & 63;
  const int wid  = tid >> 6;
  const int wr   = wid >> 1;                      // 0..1 (M)
  const int wc   = wid & 1;                       // 0..1 (N)

  // staging map: chunk c -> LDS bytes [16c,16c+16): row r=c>>3, physical
  // 16B slot (c&7) holds logical k-slot (c&7)^(r&7) -> global k-off *8.
  const u16* gsrc[8];
  int loff[8];
#pragma unroll
  for (int j = 0; j < 4; ++j) {
    int c = tid + j * 256;                        // A chunks 0..1023
    int r = c >> 3;
    int kg = ((c & 7) ^ (r & 7)) * 8;
    gsrc[j] = A + (long)(m0 + r) * lda + kg;
    loff[j] = c * 8;
  }
#pragma unroll
  for (int j = 0; j < 4; ++j) {
    int c = tid + j * 256;                        // B chunks 0..1023
    int r = c >> 3;
    int kg = ((c & 7) ^ (r & 7)) * 8;
    gsrc[4 + j] = B + (long)(n0 + r) * ldb + kg;
    loff[4 + j] = A_U16 + c * 8;
  }

#define STAGE_ALL(T_, DST_)                                                 \
  {                                                                         \
    _Pragma("unroll")                                                       \
    for (int s = 0; s < 8; ++s)                                             \
      gload_lds16(gsrc[s] + (long)(T_) * 64, (DST_) + loff[s]);             \
  }

  // ds_read swizzled byte offsets
  const int kl  = (lane >> 4) * 16;
  const int swz = (lane & 7) << 4;
  const int kx0 = kl ^ swz;
  const int kx1 = (64 + kl) ^ swz;
  const int abase = (wr * 64 + (lane & 15)) * 128;
  const int bbase = 2 * A_U16 + (wc * 64 + (lane & 15)) * 128;

  float4v acc[4][4];
#pragma unroll
  for (int i = 0; i < 4; ++i)
#pragma unroll
    for (int j = 0; j < 4; ++j)
      acc[i][j] = (float4v){0.f, 0.f, 0.f, 0.f};

  // prologue: stage tile 0 into buf 0
  STAGE_ALL(0, lds);
  asm volatile("s_waitcnt vmcnt(0)" ::: "memory");
  __builtin_amdgcn_s_barrier();

  for (int t = 0; t < nk; ++t) {
    const char* bb = (const char*)lds + (t & 1) * TILE_BYTES;
    u16* sb = lds + ((t & 1) ^ 1) * TILE_U16;

    if (t + 1 < nk) STAGE_ALL(t + 1, sb);         // issue early: max slack

    short8v a0[4], b0[4], a1[4], b1[4];
    // slice-0 read group (these 8 must be the OLDEST lgkm entries)
#pragma unroll
    for (int mi = 0; mi < 4; ++mi)
      a0[mi] = *(const short8v*)(bb + abase + mi * 2048 + kx0);
#pragma unroll
    for (int ni = 0; ni < 4; ++ni)
      b0[ni] = *(const short8v*)(bb + bbase + ni * 2048 + kx0);
    __builtin_amdgcn_sched_barrier(0);            // pin group order
    // slice-1 read group
#pragma unroll
    for (int mi = 0; mi < 4; ++mi)
      a1[mi] = *(const short8v*)(bb + abase + mi * 2048 + kx1);
#pragma unroll
    for (int ni = 0; ni < 4; ++ni)
      b1[ni] = *(const short8v*)(bb + bbase + ni * 2048 + kx1);

    asm volatile("s_waitcnt lgkmcnt(8)" ::: "memory");  // slice0 landed
    __builtin_amdgcn_sched_barrier(0);
    __builtin_amdgcn_s_setprio(1);
#pragma unroll
    for (int mi = 0; mi < 4; ++mi)
#pragma unroll
      for (int ni = 0; ni < 4; ++ni)
        acc[mi][ni] = __builtin_amdgcn_mfma_f32_16x16x32_bf16(
            a0[mi], b0[ni], acc[mi][ni], 0, 0, 0);
    __builtin_amdgcn_s_setprio(0);

    asm volatile("s_waitcnt lgkmcnt(0)" ::: "memory");  // slice1 landed
    __builtin_amdgcn_sched_barrier(0);
    __builtin_amdgcn_s_setprio(1);
#pragma unroll
    for (int mi = 0; mi < 4; ++mi)
#pragma unroll
      for (int ni = 0; ni < 4; ++ni)
        acc[mi][ni] = __builtin_amdgcn_mfma_f32_16x16x32_bf16(
            a1[mi], b1[ni], acc[mi][ni], 0, 0, 0);
    __builtin_amdgcn_s_setprio(0);

    asm volatile("s_waitcnt vmcnt(0)" ::: "memory");  // t+1's stage landed
    __builtin_amdgcn_s_barrier();                     // visible to all waves
  }
#undef STAGE_ALL

  // epilogue: C/D layout col = lane&15, row = (lane>>4)*4 + reg
  CT* c = C + (long)z * sC;
  const int r0base = m0 + wr * 64 + ((lane >> 4) << 2);
  const int cbase  = n0 + wc * 64 + (lane & 15);
#pragma unroll
  for (int mi = 0; mi < 4; ++mi) {
#pragma unroll
    for (int ni = 0; ni < 4; ++ni) {
      const int r0 = r0base + mi * 16;
      const int cc = cbase + ni * 16;
#pragma unroll
      for (int r = 0; r < 4; ++r) {
        float v = acc[mi][ni][r];
        if constexpr (__is_same(CT, float)) c[(long)(r0 + r) * ldc + cc] = v;
        else                                c[(long)(r0 + r) * ldc + cc] = f2b(v);
      }
    }
  }
}

// ---------------------------------------------------------------------------
// masked scaled softmax, in place on bf16 S (one row per block, B*T blocks).
// Row i sees j <= i+1; scale = 1/32. Zero-pads P up to the PV staged extent
// (tile base + 192, BM=128/BK=64).
// ---------------------------------------------------------------------------
__global__ __launch_bounds__(256)
void softmax_kernel(u16* __restrict__ SP, int T) {
  const int  i    = blockIdx.x & (T - 1);
  const long base = (long)blockIdx.x * T;
  const int  nvis = min(i + 2, T);
  const int  capJ = min(T, ((i >> 7) << 7) + 192);  // PV staging extent
  const float scale = 0.03125f;

  __shared__ float red[4];

  const int j0 = threadIdx.x * 8;
  float v[8];
  float m = -INFINITY;
  if (j0 < nvis) {
    short8v raw = *(const short8v*)&SP[base + j0];
#pragma unroll
    for (int e = 0; e < 8; ++e) {
      float f = (j0 + e < nvis) ? b2f((u16)raw[e]) * scale : -INFINITY;
      v[e] = f;
      m = fmaxf(m, f);
    }
  }
#pragma unroll
  for (int o = 32; o; o >>= 1) m = fmaxf(m, __shfl_xor(m, o));
  const int wid = threadIdx.x >> 6;
  if ((threadIdx.x & 63) == 0) red[wid] = m;
  __syncthreads();
  m = fmaxf(fmaxf(red[0], red[1]), fmaxf(red[2], red[3]));
  __syncthreads();

  float s = 0.f;
  if (j0 < nvis) {
#pragma unroll
    for (int e = 0; e < 8; ++e) {
      float p = (j0 + e < nvis) ? __expf(v[e] - m) : 0.f;
      v[e] = p;
      s += p;
    }
  }
#pragma unroll
  for (int o = 32; o; o >>= 1) s += __shfl_xor(s, o);
  if ((threadIdx.x & 63) == 0) red[wid] = s;
  __syncthreads();
  s = red[0] + red[1] + red[2] + red[3];
  const float inv = 1.0f / s;

  if (j0 < capJ) {
    short8v o8;
#pragma unroll
    for (int e = 0; e < 8; ++e)
      o8[e] = (short)f2b((j0 + e < nvis) ? v[e] * inv : 0.f);
    *(short8v*)&SP[base + j0] = o8;
  }
}

// ---------------------------------------------------------------------------
extern "C" void kernel_launch(void* const* d_in, const int* in_sizes, int n_in,
                              void* d_out, int out_size, void* d_ws, size_t ws_size,
                              hipStream_t stream) {
  const float* x  = (const float*)d_in[0];
  const float* Wq = (const float*)d_in[1];
  const float* Wk = (const float*)d_in[2];
  const float* Wv = (const float*)d_in[3];
  float* out = (float*)d_out;

  const int B = 4, T = 2048, D = 1024;
  const int M = B * T;          // 8192
  const long TT = (long)T * T;  // 4 Mi elements

  char* ws = (char*)d_ws;
  u16* qk  = (u16*)(ws);                      // 32 MiB: [8192][2048], q|k
  u16* vt  = (u16*)(ws + (32l << 20));        // 16 MiB: [1024][8192] d-major
  u16* xb  = (u16*)(ws + (48l << 20));        // 16 MiB (dead after vt GEMM)
  u16* wqk = (u16*)(ws + (64l << 20));        //  4 MiB: [2048][1024]
  u16* wv  = (u16*)(ws + (68l << 20));        //  2 MiB
  u16* S   = (u16*)(ws + (48l << 20));        // 32 MiB: 4 x [2048][2048] bf16
                                              //   (overlaps xb/wqk/wv; written
                                              //    only after they are dead)
  // peak: 80 MiB

  // fp32 -> bf16
  cvt_f32_bf16<<<2048, 256, 0, stream>>>(x, xb, (M * D) / 4);
  cvt_w3<<<3 * (D * D / 4) / 256, 256, 0, stream>>>(
      Wq, Wk, Wv, wqk, wqk + (long)D * D, wv, D * D / 4);

  // qk = x @ [Wq;Wk]^T  (8192 x 2048): grid 64x16
  gemm8<0, u16><<<dim3(M / 128, 2 * D / 128, 1), 256, 0, stream>>>(
      xb, D, 0, wqk, D, 0, qk, 2 * D, 0, D);
  // vt = Wv @ x^T  (1024 x 8192, d-major): grid 8x64
  gemm8<0, u16><<<dim3(D / 128, M / 128, 1), 256, 0, stream>>>(
      wv, D, 0, xb, D, 0, vt, M, 0, D);

  // S_b = q_b k_b^T (bf16, tile-skip above diagonal): grid 16x16x4, 604 live
  gemm8<1, u16><<<dim3(T / 128, T / 128, B), 256, 0, stream>>>(
      qk, 2 * D, (long)T * 2 * D,
      qk + D, 2 * D, (long)T * 2 * D,
      S, T, TT, D);

  // softmax in place (S -> P), all rows of all batches
  softmax_kernel<<<B * T, 256, 0, stream>>>(S, T);

  // O_b = P_b V_b = P_b (vt_b)^T, K capped per tile-row: grid 16x8x4
  gemm8<2, float><<<dim3(T / 128, D / 128, B), 256, 0, stream>>>(
      S, T, TT,
      vt, M, T,
      out, D, (long)T * D, T);
}